// Round 1
// baseline (2543.952 us; speedup 1.0000x reference)
//
#include <hip/hip_runtime.h>

typedef __attribute__((ext_vector_type(8))) short short8;
typedef __attribute__((ext_vector_type(4))) float floatx4;

__device__ inline unsigned short f2bf(float f) {
  union { float f; unsigned u; } x; x.f = f;
  unsigned r = x.u + 0x7FFFu + ((x.u >> 16) & 1u);
  return (unsigned short)(r >> 16);
}

// ---------------- W transpose + bf16 convert: W[k][q][c] -> Wt[k][c][q] ----------------
__global__ __launch_bounds__(256) void convw_kernel(const float* __restrict__ W1,
                                                    const float* __restrict__ W2,
                                                    unsigned short* __restrict__ W1t,
                                                    unsigned short* __restrict__ W2t) {
  int idx = blockIdx.x * 256 + threadIdx.x;
  const int n1 = 27 * 96 * 64;
  const int n2 = 27 * 64 * 64;
  if (idx < n1) {
    int k = idx / (96 * 64);
    int r = idx % (96 * 64);
    int q = r / 64, c = r % 64;
    W1t[((size_t)k * 64 + c) * 96 + q] = f2bf(W1[idx]);
  } else if (idx < n1 + n2) {
    int j = idx - n1;
    int k = j / 4096;
    int r = j % 4096;
    int q = r / 64, c = r % 64;
    W2t[((size_t)k * 64 + c) * 64 + q] = f2bf(W2[j]);
  }
}

// ---------------- Upsample: up_raw[i] = x1[up_src[i]] @ W_up[up_off[i]] ----------------
__global__ __launch_bounds__(256) void up_kernel(const float* __restrict__ x1,
                                                 const int* __restrict__ up_src,
                                                 const int* __restrict__ up_off,
                                                 const float* __restrict__ Wup,
                                                 float* __restrict__ up_raw,
                                                 float* __restrict__ part1,
                                                 float* __restrict__ part2,
                                                 int N) {
  __shared__ float rowbuf[8][96];
  __shared__ int offbuf[8];
  __shared__ float red[8][32];
  const int tid = threadIdx.x;
  const int c = tid & 31;
  const int slot = tid >> 5;
  float s1 = 0.f, s2 = 0.f;

  for (int i0 = blockIdx.x * 8; i0 < N; i0 += gridDim.x * 8) {
    for (int j = tid; j < 8 * 96; j += 256) {
      int r = j / 96, q = j % 96;
      int row = i0 + r;
      float v = 0.f;
      if (row < N) {
        int s = up_src[row];
        v = x1[(size_t)s * 96 + q];
      }
      rowbuf[r][q] = v;
    }
    if (tid < 8) offbuf[tid] = (i0 + tid < N) ? up_off[i0 + tid] : 0;
    __syncthreads();
    int row = i0 + slot;
    float acc = 0.f;
    const float* w = Wup + (size_t)offbuf[slot] * 96 * 32 + c;
    #pragma unroll 8
    for (int q = 0; q < 96; ++q) acc = fmaf(rowbuf[slot][q], w[(size_t)q * 32], acc);
    if (row < N) {
      up_raw[(size_t)row * 32 + c] = acc;
      s1 += acc;
      s2 += acc * acc;
    }
    __syncthreads();
  }
  red[slot][c] = s1;
  __syncthreads();
  if (slot == 0) {
    float t = 0.f;
    for (int r = 0; r < 8; ++r) t += red[r][c];
    part1[(size_t)blockIdx.x * 32 + c] = t;
  }
  __syncthreads();
  red[slot][c] = s2;
  __syncthreads();
  if (slot == 0) {
    float t = 0.f;
    for (int r = 0; r < 8; ++r) t += red[r][c];
    part2[(size_t)blockIdx.x * 32 + c] = t;
  }
}

// ---------------- BN finalize: partials -> scale/bias ----------------
template <int C>
__global__ void bn_finalize(const float* __restrict__ part1, const float* __restrict__ part2,
                            int nP, const float* __restrict__ g, const float* __restrict__ b,
                            float* __restrict__ sb, int N) {
  int c = threadIdx.x;
  if (c >= C) return;
  float s1 = 0.f, s2 = 0.f;
  for (int p = 0; p < nP; ++p) {
    s1 += part1[(size_t)p * C + c];
    s2 += part2[(size_t)p * C + c];
  }
  float mean = s1 / (float)N;
  float var = s2 / (float)N - mean * mean;
  float sc = g[c] * rsqrtf(var + 1e-5f);
  sb[c] = sc;
  sb[C + c] = b[c] - mean * sc;
}

// ---------------- Concat: x_bf16 = [bnrelu(up), x2, x3] ----------------
__global__ __launch_bounds__(256) void concat_kernel(const float* __restrict__ up_raw,
                                                     const float* __restrict__ x2,
                                                     const float* __restrict__ x3,
                                                     const float* __restrict__ sb,
                                                     unsigned short* __restrict__ xb,
                                                     int N) {
  int total = N * 96;
  for (int idx = blockIdx.x * 256 + threadIdx.x; idx < total; idx += gridDim.x * 256) {
    int i = idx / 96, c = idx % 96;
    float v;
    if (c < 32) {
      v = fmaxf(up_raw[(size_t)i * 32 + c] * sb[c] + sb[32 + c], 0.f);
    } else if (c < 64) {
      v = x2[(size_t)i * 32 + (c - 32)];
    } else {
      v = x3[(size_t)i * 32 + (c - 64)];
    }
    xb[idx] = f2bf(v);
  }
}

// ---------------- SubM conv: y[i] = sum_k gather(feats, nbr[i,k]) @ W[k] ----------------
template <int CIN>
__global__ __launch_bounds__(256) void conv_kernel(const unsigned short* __restrict__ feats,
                                                   const unsigned short* __restrict__ Wt,
                                                   const int* __restrict__ nbr,
                                                   float* __restrict__ yraw,
                                                   float* __restrict__ part1,
                                                   float* __restrict__ part2,
                                                   int N) {
  constexpr int PAD = CIN + 8;
  constexpr int CPR = CIN / 8;  // 16B chunks per row
  __shared__ unsigned short Al[64 * PAD];
  __shared__ unsigned short Bl[64 * PAD];
  __shared__ float wsum[4][64];
  __shared__ float wsq[4][64];

  const int tid = threadIdx.x;
  const int wv = tid >> 6;
  const int lane = tid & 63;
  const int lr = lane & 15;
  const int lg = lane >> 4;
  const int base = blockIdx.x * 64;

  floatx4 acc[4];
  #pragma unroll
  for (int i = 0; i < 4; ++i) acc[i] = (floatx4){0.f, 0.f, 0.f, 0.f};

  for (int k = 0; k < 27; ++k) {
    // stage W^T tile (B): 64 cols x CIN
    #pragma unroll
    for (int ch = tid; ch < 64 * CPR; ch += 256) {
      int col = ch / CPR, j = ch % CPR;
      const uint4* src = (const uint4*)(Wt + ((size_t)k * 64 + col) * CIN);
      *(uint4*)(&Bl[col * PAD + j * 8]) = src[j];
    }
    // stage gathered A tile: 64 rows x CIN
    #pragma unroll
    for (int ch = tid; ch < 64 * CPR; ch += 256) {
      int r = ch / CPR, j = ch % CPR;
      int row = base + r;
      int g = (row < N) ? nbr[(size_t)row * 27 + k] : -1;
      uint4 v = {0u, 0u, 0u, 0u};
      if (g >= 0) v = ((const uint4*)(feats + (size_t)g * CIN))[j];
      *(uint4*)(&Al[r * PAD + j * 8]) = v;
    }
    __syncthreads();
    #pragma unroll
    for (int kk = 0; kk < CIN; kk += 32) {
      short8 a = *(const short8*)(&Al[(wv * 16 + lr) * PAD + kk + lg * 8]);
      #pragma unroll
      for (int ct = 0; ct < 4; ++ct) {
        short8 b = *(const short8*)(&Bl[(ct * 16 + lr) * PAD + kk + lg * 8]);
        acc[ct] = __builtin_amdgcn_mfma_f32_16x16x32_bf16(a, b, acc[ct], 0, 0, 0);
      }
    }
    __syncthreads();
  }

  // epilogue: write raw output + per-column partial sums for BN
  float cs[4], cq[4];
  #pragma unroll
  for (int ct = 0; ct < 4; ++ct) {
    cs[ct] = 0.f;
    cq[ct] = 0.f;
    #pragma unroll
    for (int reg = 0; reg < 4; ++reg) {
      float v = acc[ct][reg];
      int row = base + wv * 16 + lg * 4 + reg;
      if (row < N) yraw[(size_t)row * 64 + ct * 16 + lr] = v;
      cs[ct] += v;
      cq[ct] += v * v;
    }
  }
  #pragma unroll
  for (int ct = 0; ct < 4; ++ct) {
    float a = cs[ct], b = cq[ct];
    a += __shfl_xor(a, 16);
    a += __shfl_xor(a, 32);
    b += __shfl_xor(b, 16);
    b += __shfl_xor(b, 32);
    if (lg == 0) {
      wsum[wv][ct * 16 + lr] = a;
      wsq[wv][ct * 16 + lr] = b;
    }
  }
  __syncthreads();
  if (tid < 64) {
    float s1 = wsum[0][tid] + wsum[1][tid] + wsum[2][tid] + wsum[3][tid];
    float s2 = wsq[0][tid] + wsq[1][tid] + wsq[2][tid] + wsq[3][tid];
    part1[(size_t)blockIdx.x * 64 + tid] = s1;
    part2[(size_t)blockIdx.x * 64 + tid] = s2;
  }
}

// ---------------- Apply BN+ReLU, fp32 -> bf16 ----------------
__global__ __launch_bounds__(256) void apply_bn_bf16(const float* __restrict__ yraw,
                                                     const float* __restrict__ sb,
                                                     unsigned short* __restrict__ out,
                                                     int N) {
  int total = N * 64;
  for (int idx = blockIdx.x * 256 + threadIdx.x; idx < total; idx += gridDim.x * 256) {
    int c = idx & 63;
    float v = fmaxf(yraw[idx] * sb[c] + sb[64 + c], 0.f);
    out[idx] = f2bf(v);
  }
}

// ---------------- Apply BN+ReLU in place, fp32 ----------------
__global__ __launch_bounds__(256) void apply_bn_inplace(float* __restrict__ y,
                                                        const float* __restrict__ sb,
                                                        int N) {
  int total = N * 64;
  for (int idx = blockIdx.x * 256 + threadIdx.x; idx < total; idx += gridDim.x * 256) {
    int c = idx & 63;
    y[idx] = fmaxf(y[idx] * sb[c] + sb[64 + c], 0.f);
  }
}

extern "C" void kernel_launch(void* const* d_in, const int* in_sizes, int n_in,
                              void* d_out, int out_size, void* d_ws, size_t ws_size,
                              hipStream_t stream) {
  const float* x1 = (const float*)d_in[0];
  const float* x2 = (const float*)d_in[1];
  const float* x3 = (const float*)d_in[2];
  const float* Wup = (const float*)d_in[3];
  const float* gup = (const float*)d_in[4];
  const float* bup = (const float*)d_in[5];
  const float* W1 = (const float*)d_in[6];
  const float* g1 = (const float*)d_in[7];
  const float* b1 = (const float*)d_in[8];
  const float* W2 = (const float*)d_in[9];
  const float* g2 = (const float*)d_in[10];
  const float* b2 = (const float*)d_in[11];
  const int* up_src = (const int*)d_in[12];
  const int* up_off = (const int*)d_in[13];
  const int* nbr = (const int*)d_in[14];

  const int N = in_sizes[12];
  const int NB = (N + 63) / 64;

  char* ws = (char*)d_ws;
  size_t off = 0;
  auto alloc = [&](size_t bytes) -> void* {
    void* p = ws + off;
    off = (off + bytes + 255) & ~(size_t)255;
    return p;
  };

  unsigned short* xb   = (unsigned short*)alloc((size_t)N * 96 * 2);
  unsigned short* y1b  = (unsigned short*)alloc((size_t)N * 64 * 2);
  float* yraw          = (float*)alloc((size_t)N * 64 * 4);  // also up_raw (N*32 floats)
  unsigned short* W1t  = (unsigned short*)alloc((size_t)27 * 64 * 96 * 2);
  unsigned short* W2t  = (unsigned short*)alloc((size_t)27 * 64 * 64 * 2);
  float* upP1          = (float*)alloc((size_t)1024 * 32 * 4);
  float* upP2          = (float*)alloc((size_t)1024 * 32 * 4);
  float* c1P1          = (float*)alloc((size_t)NB * 64 * 4);
  float* c1P2          = (float*)alloc((size_t)NB * 64 * 4);
  float* c2P1          = (float*)alloc((size_t)NB * 64 * 4);
  float* c2P2          = (float*)alloc((size_t)NB * 64 * 4);
  float* sbup          = (float*)alloc(64 * 4);
  float* sb1           = (float*)alloc(128 * 4);
  float* sb2           = (float*)alloc(128 * 4);
  (void)ws_size;

  float* out = (float*)d_out;

  // 1. W -> bf16 transposed
  convw_kernel<<<1080, 256, 0, stream>>>(W1, W2, W1t, W2t);
  // 2. upsample
  up_kernel<<<1024, 256, 0, stream>>>(x1, up_src, up_off, Wup, yraw, upP1, upP2, N);
  // 3. BN(up) finalize
  bn_finalize<32><<<1, 32, 0, stream>>>(upP1, upP2, 1024, gup, bup, sbup, N);
  // 4. concat -> bf16
  concat_kernel<<<2048, 256, 0, stream>>>(yraw, x2, x3, sbup, xb, N);
  // 5. conv1
  conv_kernel<96><<<NB, 256, 0, stream>>>(xb, W1t, nbr, yraw, c1P1, c1P2, N);
  // 6. BN1 finalize
  bn_finalize<64><<<1, 64, 0, stream>>>(c1P1, c1P2, NB, g1, b1, sb1, N);
  // 7. apply BN1 -> bf16
  apply_bn_bf16<<<2048, 256, 0, stream>>>(yraw, sb1, y1b, N);
  // 8. conv2 (raw output into d_out)
  conv_kernel<64><<<NB, 256, 0, stream>>>(y1b, W2t, nbr, out, c2P1, c2P2, N);
  // 9. BN2 finalize
  bn_finalize<64><<<1, 64, 0, stream>>>(c2P1, c2P2, NB, g2, b2, sb2, N);
  // 10. apply BN2 in place (fp32)
  apply_bn_inplace<<<2048, 256, 0, stream>>>(out, sb2, N);
}

// Round 2
// 818.617 us; speedup vs baseline: 3.1076x; 3.1076x over previous
//
#include <hip/hip_runtime.h>

typedef __attribute__((ext_vector_type(8))) short short8;
typedef __attribute__((ext_vector_type(4))) float floatx4;

__device__ inline unsigned short f2bf(float f) {
  union { float f; unsigned u; } x; x.f = f;
  unsigned r = x.u + 0x7FFFu + ((x.u >> 16) & 1u);
  return (unsigned short)(r >> 16);
}

// ---------------- W transpose + bf16 convert: W[k][q][c] -> Wt[k][c][q] ----------------
__global__ __launch_bounds__(256) void convw_kernel(const float* __restrict__ W1,
                                                    const float* __restrict__ W2,
                                                    unsigned short* __restrict__ W1t,
                                                    unsigned short* __restrict__ W2t) {
  int idx = blockIdx.x * 256 + threadIdx.x;
  const int n1 = 27 * 96 * 64;
  const int n2 = 27 * 64 * 64;
  if (idx < n1) {
    int k = idx / (96 * 64);
    int r = idx % (96 * 64);
    int q = r / 64, c = r % 64;
    W1t[((size_t)k * 64 + c) * 96 + q] = f2bf(W1[idx]);
  } else if (idx < n1 + n2) {
    int j = idx - n1;
    int k = j / 4096;
    int r = j % 4096;
    int q = r / 64, c = r % 64;
    W2t[((size_t)k * 64 + c) * 64 + q] = f2bf(W2[j]);
  }
}

// ---------------- Upsample: up_raw[i] = x1[up_src[i]] @ W_up[up_off[i]] ----------------
__global__ __launch_bounds__(256) void up_kernel(const float* __restrict__ x1,
                                                 const int* __restrict__ up_src,
                                                 const int* __restrict__ up_off,
                                                 const float* __restrict__ Wup,
                                                 float* __restrict__ up_raw,
                                                 float* __restrict__ part1,
                                                 float* __restrict__ part2,
                                                 int N) {
  __shared__ float rowbuf[8][96];
  __shared__ int offbuf[8];
  __shared__ float red[8][32];
  const int tid = threadIdx.x;
  const int c = tid & 31;
  const int slot = tid >> 5;
  float s1 = 0.f, s2 = 0.f;

  for (int i0 = blockIdx.x * 8; i0 < N; i0 += gridDim.x * 8) {
    for (int j = tid; j < 8 * 96; j += 256) {
      int r = j / 96, q = j % 96;
      int row = i0 + r;
      float v = 0.f;
      if (row < N) {
        int s = up_src[row];
        v = x1[(size_t)s * 96 + q];
      }
      rowbuf[r][q] = v;
    }
    if (tid < 8) offbuf[tid] = (i0 + tid < N) ? up_off[i0 + tid] : 0;
    __syncthreads();
    int row = i0 + slot;
    float acc = 0.f;
    const float* w = Wup + (size_t)offbuf[slot] * 96 * 32 + c;
    #pragma unroll 8
    for (int q = 0; q < 96; ++q) acc = fmaf(rowbuf[slot][q], w[(size_t)q * 32], acc);
    if (row < N) {
      up_raw[(size_t)row * 32 + c] = acc;
      s1 += acc;
      s2 += acc * acc;
    }
    __syncthreads();
  }
  red[slot][c] = s1;
  __syncthreads();
  if (slot == 0) {
    float t = 0.f;
    for (int r = 0; r < 8; ++r) t += red[r][c];
    part1[(size_t)blockIdx.x * 32 + c] = t;
  }
  __syncthreads();
  red[slot][c] = s2;
  __syncthreads();
  if (slot == 0) {
    float t = 0.f;
    for (int r = 0; r < 8; ++r) t += red[r][c];
    part2[(size_t)blockIdx.x * 32 + c] = t;
  }
}

// ---------------- BN finalize: partials -> scale/bias (parallel reduce) ----------------
template <int C>
__global__ __launch_bounds__(1024) void bn_finalize(const float* __restrict__ part1,
                                                    const float* __restrict__ part2,
                                                    int nP, const float* __restrict__ g,
                                                    const float* __restrict__ b,
                                                    float* __restrict__ sb, int N) {
  constexpr int R = 1024 / C;  // rows of threads per column
  __shared__ float red1[1024];
  __shared__ float red2[1024];
  const int tid = threadIdx.x;
  const int c = tid % C;       // consecutive tids -> consecutive columns (coalesced)
  const int r = tid / C;
  float s1 = 0.f, s2 = 0.f;
  for (int p = r; p < nP; p += R) {
    s1 += part1[(size_t)p * C + c];
    s2 += part2[(size_t)p * C + c];
  }
  red1[tid] = s1;
  red2[tid] = s2;
  __syncthreads();
  #pragma unroll
  for (int step = R / 2; step > 0; step >>= 1) {
    if (r < step) {
      red1[tid] += red1[tid + step * C];
      red2[tid] += red2[tid + step * C];
    }
    __syncthreads();
  }
  if (r == 0) {
    float mean = red1[c] / (float)N;
    float var = red2[c] / (float)N - mean * mean;
    float sc = g[c] * rsqrtf(var + 1e-5f);
    sb[c] = sc;
    sb[C + c] = b[c] - mean * sc;
  }
}

// ---------------- Concat: x_bf16 = [bnrelu(up), x2, x3] ----------------
__global__ __launch_bounds__(256) void concat_kernel(const float* __restrict__ up_raw,
                                                     const float* __restrict__ x2,
                                                     const float* __restrict__ x3,
                                                     const float* __restrict__ sb,
                                                     unsigned short* __restrict__ xb,
                                                     int N) {
  int total = N * 96;
  for (int idx = blockIdx.x * 256 + threadIdx.x; idx < total; idx += gridDim.x * 256) {
    int i = idx / 96, c = idx % 96;
    float v;
    if (c < 32) {
      v = fmaxf(up_raw[(size_t)i * 32 + c] * sb[c] + sb[32 + c], 0.f);
    } else if (c < 64) {
      v = x2[(size_t)i * 32 + (c - 32)];
    } else {
      v = x3[(size_t)i * 32 + (c - 64)];
    }
    xb[idx] = f2bf(v);
  }
}

// ---------------- SubM conv: y[i] = sum_k gather(feats, nbr[i,k]) @ W[k] ----------------
template <int CIN>
__global__ __launch_bounds__(256) void conv_kernel(const unsigned short* __restrict__ feats,
                                                   const unsigned short* __restrict__ Wt,
                                                   const int* __restrict__ nbr,
                                                   float* __restrict__ yraw,
                                                   float* __restrict__ part1,
                                                   float* __restrict__ part2,
                                                   int N) {
  constexpr int PAD = CIN + 8;
  constexpr int CPR = CIN / 8;  // 16B chunks per row
  __shared__ unsigned short Al[64 * PAD];
  __shared__ unsigned short Bl[64 * PAD];
  __shared__ float wsum[4][64];
  __shared__ float wsq[4][64];

  const int tid = threadIdx.x;
  const int wv = tid >> 6;
  const int lane = tid & 63;
  const int lr = lane & 15;
  const int lg = lane >> 4;
  const int base = blockIdx.x * 64;

  floatx4 acc[4];
  #pragma unroll
  for (int i = 0; i < 4; ++i) acc[i] = (floatx4){0.f, 0.f, 0.f, 0.f};

  for (int k = 0; k < 27; ++k) {
    // stage W^T tile (B): 64 cols x CIN
    #pragma unroll
    for (int ch = tid; ch < 64 * CPR; ch += 256) {
      int col = ch / CPR, j = ch % CPR;
      const uint4* src = (const uint4*)(Wt + ((size_t)k * 64 + col) * CIN);
      *(uint4*)(&Bl[col * PAD + j * 8]) = src[j];
    }
    // stage gathered A tile: 64 rows x CIN
    #pragma unroll
    for (int ch = tid; ch < 64 * CPR; ch += 256) {
      int r = ch / CPR, j = ch % CPR;
      int row = base + r;
      int g = (row < N) ? nbr[(size_t)row * 27 + k] : -1;
      uint4 v = {0u, 0u, 0u, 0u};
      if (g >= 0) v = ((const uint4*)(feats + (size_t)g * CIN))[j];
      *(uint4*)(&Al[r * PAD + j * 8]) = v;
    }
    __syncthreads();
    #pragma unroll
    for (int kk = 0; kk < CIN; kk += 32) {
      short8 a = *(const short8*)(&Al[(wv * 16 + lr) * PAD + kk + lg * 8]);
      #pragma unroll
      for (int ct = 0; ct < 4; ++ct) {
        short8 b = *(const short8*)(&Bl[(ct * 16 + lr) * PAD + kk + lg * 8]);
        acc[ct] = __builtin_amdgcn_mfma_f32_16x16x32_bf16(a, b, acc[ct], 0, 0, 0);
      }
    }
    __syncthreads();
  }

  // epilogue: write raw output + per-column partial sums for BN
  float cs[4], cq[4];
  #pragma unroll
  for (int ct = 0; ct < 4; ++ct) {
    cs[ct] = 0.f;
    cq[ct] = 0.f;
    #pragma unroll
    for (int reg = 0; reg < 4; ++reg) {
      float v = acc[ct][reg];
      int row = base + wv * 16 + lg * 4 + reg;
      if (row < N) yraw[(size_t)row * 64 + ct * 16 + lr] = v;
      cs[ct] += v;
      cq[ct] += v * v;
    }
  }
  #pragma unroll
  for (int ct = 0; ct < 4; ++ct) {
    float a = cs[ct], b = cq[ct];
    a += __shfl_xor(a, 16);
    a += __shfl_xor(a, 32);
    b += __shfl_xor(b, 16);
    b += __shfl_xor(b, 32);
    if (lg == 0) {
      wsum[wv][ct * 16 + lr] = a;
      wsq[wv][ct * 16 + lr] = b;
    }
  }
  __syncthreads();
  if (tid < 64) {
    float s1 = wsum[0][tid] + wsum[1][tid] + wsum[2][tid] + wsum[3][tid];
    float s2 = wsq[0][tid] + wsq[1][tid] + wsq[2][tid] + wsq[3][tid];
    part1[(size_t)blockIdx.x * 64 + tid] = s1;
    part2[(size_t)blockIdx.x * 64 + tid] = s2;
  }
}

// ---------------- Apply BN+ReLU, fp32 -> bf16 ----------------
__global__ __launch_bounds__(256) void apply_bn_bf16(const float* __restrict__ yraw,
                                                     const float* __restrict__ sb,
                                                     unsigned short* __restrict__ out,
                                                     int N) {
  int total = N * 64;
  for (int idx = blockIdx.x * 256 + threadIdx.x; idx < total; idx += gridDim.x * 256) {
    int c = idx & 63;
    float v = fmaxf(yraw[idx] * sb[c] + sb[64 + c], 0.f);
    out[idx] = f2bf(v);
  }
}

// ---------------- Apply BN+ReLU in place, fp32 ----------------
__global__ __launch_bounds__(256) void apply_bn_inplace(float* __restrict__ y,
                                                        const float* __restrict__ sb,
                                                        int N) {
  int total = N * 64;
  for (int idx = blockIdx.x * 256 + threadIdx.x; idx < total; idx += gridDim.x * 256) {
    int c = idx & 63;
    y[idx] = fmaxf(y[idx] * sb[c] + sb[64 + c], 0.f);
  }
}

extern "C" void kernel_launch(void* const* d_in, const int* in_sizes, int n_in,
                              void* d_out, int out_size, void* d_ws, size_t ws_size,
                              hipStream_t stream) {
  const float* x1 = (const float*)d_in[0];
  const float* x2 = (const float*)d_in[1];
  const float* x3 = (const float*)d_in[2];
  const float* Wup = (const float*)d_in[3];
  const float* gup = (const float*)d_in[4];
  const float* bup = (const float*)d_in[5];
  const float* W1 = (const float*)d_in[6];
  const float* g1 = (const float*)d_in[7];
  const float* b1 = (const float*)d_in[8];
  const float* W2 = (const float*)d_in[9];
  const float* g2 = (const float*)d_in[10];
  const float* b2 = (const float*)d_in[11];
  const int* up_src = (const int*)d_in[12];
  const int* up_off = (const int*)d_in[13];
  const int* nbr = (const int*)d_in[14];

  const int N = in_sizes[12];
  const int NB = (N + 63) / 64;

  char* ws = (char*)d_ws;
  size_t off = 0;
  auto alloc = [&](size_t bytes) -> void* {
    void* p = ws + off;
    off = (off + bytes + 255) & ~(size_t)255;
    return p;
  };

  unsigned short* xb   = (unsigned short*)alloc((size_t)N * 96 * 2);
  unsigned short* y1b  = (unsigned short*)alloc((size_t)N * 64 * 2);
  float* yraw          = (float*)alloc((size_t)N * 64 * 4);  // also up_raw (N*32 floats)
  unsigned short* W1t  = (unsigned short*)alloc((size_t)27 * 64 * 96 * 2);
  unsigned short* W2t  = (unsigned short*)alloc((size_t)27 * 64 * 64 * 2);
  float* upP1          = (float*)alloc((size_t)1024 * 32 * 4);
  float* upP2          = (float*)alloc((size_t)1024 * 32 * 4);
  float* c1P1          = (float*)alloc((size_t)NB * 64 * 4);
  float* c1P2          = (float*)alloc((size_t)NB * 64 * 4);
  float* c2P1          = (float*)alloc((size_t)NB * 64 * 4);
  float* c2P2          = (float*)alloc((size_t)NB * 64 * 4);
  float* sbup          = (float*)alloc(64 * 4);
  float* sb1           = (float*)alloc(128 * 4);
  float* sb2           = (float*)alloc(128 * 4);
  (void)ws_size;

  float* out = (float*)d_out;

  // 1. W -> bf16 transposed
  convw_kernel<<<1080, 256, 0, stream>>>(W1, W2, W1t, W2t);
  // 2. upsample
  up_kernel<<<1024, 256, 0, stream>>>(x1, up_src, up_off, Wup, yraw, upP1, upP2, N);
  // 3. BN(up) finalize
  bn_finalize<32><<<1, 1024, 0, stream>>>(upP1, upP2, 1024, gup, bup, sbup, N);
  // 4. concat -> bf16
  concat_kernel<<<2048, 256, 0, stream>>>(yraw, x2, x3, sbup, xb, N);
  // 5. conv1
  conv_kernel<96><<<NB, 256, 0, stream>>>(xb, W1t, nbr, yraw, c1P1, c1P2, N);
  // 6. BN1 finalize
  bn_finalize<64><<<1, 1024, 0, stream>>>(c1P1, c1P2, NB, g1, b1, sb1, N);
  // 7. apply BN1 -> bf16
  apply_bn_bf16<<<2048, 256, 0, stream>>>(yraw, sb1, y1b, N);
  // 8. conv2 (raw output into d_out)
  conv_kernel<64><<<NB, 256, 0, stream>>>(y1b, W2t, nbr, out, c2P1, c2P2, N);
  // 9. BN2 finalize
  bn_finalize<64><<<1, 1024, 0, stream>>>(c2P1, c2P2, NB, g2, b2, sb2, N);
  // 10. apply BN2 in place (fp32)
  apply_bn_inplace<<<2048, 256, 0, stream>>>(out, sb2, N);
}

// Round 3
// 770.216 us; speedup vs baseline: 3.3029x; 1.0628x over previous
//
#include <hip/hip_runtime.h>

typedef __attribute__((ext_vector_type(8))) short short8;
typedef __attribute__((ext_vector_type(4))) float floatx4;

__device__ inline unsigned short f2bf(float f) {
  union { float f; unsigned u; } x; x.f = f;
  unsigned r = x.u + 0x7FFFu + ((x.u >> 16) & 1u);
  return (unsigned short)(r >> 16);
}
__device__ inline float bf2f(unsigned short h) {
  union { unsigned u; float f; } x; x.u = ((unsigned)h) << 16;
  return x.f;
}

#define GLL16(g, l)                                                  \
  __builtin_amdgcn_global_load_lds(                                  \
      (const __attribute__((address_space(1))) void*)(g),            \
      (__attribute__((address_space(3))) void*)(l), 16, 0, 0)

// ---------------- W transpose + bf16 convert (+ zeropage init) ----------------
// W1t[k][c][q] linear; W2t[k][c][*] with chunk-XOR swizzle: chunk j of col c stored at j^(c&7)
__global__ __launch_bounds__(256) void convw_kernel(const float* __restrict__ W1,
                                                    const float* __restrict__ W2,
                                                    unsigned short* __restrict__ W1t,
                                                    unsigned short* __restrict__ W2t,
                                                    unsigned short* __restrict__ zp) {
  int idx = blockIdx.x * 256 + threadIdx.x;
  const int n1 = 27 * 96 * 64;
  const int n2 = 27 * 64 * 64;
  if (idx < n1) {
    int k = idx / (96 * 64);
    int r = idx % (96 * 64);
    int q = r / 64, c = r % 64;
    W1t[((size_t)k * 64 + c) * 96 + q] = f2bf(W1[idx]);
  } else if (idx < n1 + n2) {
    int j = idx - n1;
    int k = j / 4096;
    int r = j % 4096;
    int q = r / 64, c = r % 64;
    int qs = (((q >> 3) ^ (c & 7)) << 3) | (q & 7);
    W2t[((size_t)k * 64 + c) * 64 + qs] = f2bf(W2[j]);
  } else if (idx < n1 + n2 + 128) {
    zp[idx - n1 - n2] = 0;
  }
}

// ---------------- Upsample ----------------
__global__ __launch_bounds__(256) void up_kernel(const float* __restrict__ x1,
                                                 const int* __restrict__ up_src,
                                                 const int* __restrict__ up_off,
                                                 const float* __restrict__ Wup,
                                                 float* __restrict__ up_raw,
                                                 float* __restrict__ part1,
                                                 float* __restrict__ part2,
                                                 int N) {
  __shared__ float rowbuf[8][96];
  __shared__ int offbuf[8];
  __shared__ float red[8][32];
  const int tid = threadIdx.x;
  const int c = tid & 31;
  const int slot = tid >> 5;
  float s1 = 0.f, s2 = 0.f;

  for (int i0 = blockIdx.x * 8; i0 < N; i0 += gridDim.x * 8) {
    for (int j = tid; j < 8 * 96; j += 256) {
      int r = j / 96, q = j % 96;
      int row = i0 + r;
      float v = 0.f;
      if (row < N) {
        int s = up_src[row];
        v = x1[(size_t)s * 96 + q];
      }
      rowbuf[r][q] = v;
    }
    if (tid < 8) offbuf[tid] = (i0 + tid < N) ? up_off[i0 + tid] : 0;
    __syncthreads();
    int row = i0 + slot;
    float acc = 0.f;
    const float* w = Wup + (size_t)offbuf[slot] * 96 * 32 + c;
    #pragma unroll 8
    for (int q = 0; q < 96; ++q) acc = fmaf(rowbuf[slot][q], w[(size_t)q * 32], acc);
    if (row < N) {
      up_raw[(size_t)row * 32 + c] = acc;
      s1 += acc;
      s2 += acc * acc;
    }
    __syncthreads();
  }
  red[slot][c] = s1;
  __syncthreads();
  if (slot == 0) {
    float t = 0.f;
    for (int r = 0; r < 8; ++r) t += red[r][c];
    part1[(size_t)blockIdx.x * 32 + c] = t;
  }
  __syncthreads();
  red[slot][c] = s2;
  __syncthreads();
  if (slot == 0) {
    float t = 0.f;
    for (int r = 0; r < 8; ++r) t += red[r][c];
    part2[(size_t)blockIdx.x * 32 + c] = t;
  }
}

// ---------------- BN finalize (parallel reduce) ----------------
template <int C>
__global__ __launch_bounds__(1024) void bn_finalize(const float* __restrict__ part1,
                                                    const float* __restrict__ part2,
                                                    int nP, const float* __restrict__ g,
                                                    const float* __restrict__ b,
                                                    float* __restrict__ sb, int N) {
  constexpr int R = 1024 / C;
  __shared__ float red1[1024];
  __shared__ float red2[1024];
  const int tid = threadIdx.x;
  const int c = tid % C;
  const int r = tid / C;
  float s1 = 0.f, s2 = 0.f;
  for (int p = r; p < nP; p += R) {
    s1 += part1[(size_t)p * C + c];
    s2 += part2[(size_t)p * C + c];
  }
  red1[tid] = s1;
  red2[tid] = s2;
  __syncthreads();
  #pragma unroll
  for (int step = R / 2; step > 0; step >>= 1) {
    if (r < step) {
      red1[tid] += red1[tid + step * C];
      red2[tid] += red2[tid + step * C];
    }
    __syncthreads();
  }
  if (r == 0) {
    float mean = red1[c] / (float)N;
    float var = red2[c] / (float)N - mean * mean;
    float sc = g[c] * rsqrtf(var + 1e-5f);
    sb[c] = sc;
    sb[C + c] = b[c] - mean * sc;
  }
}

// ---------------- Concat (vectorized, 8 ch / thread) ----------------
__global__ __launch_bounds__(256) void concat_kernel(const float* __restrict__ up_raw,
                                                     const float* __restrict__ x2,
                                                     const float* __restrict__ x3,
                                                     const float* __restrict__ sb,
                                                     unsigned short* __restrict__ xb,
                                                     int N) {
  int total = N * 12;
  for (int idx = blockIdx.x * 256 + threadIdx.x; idx < total; idx += gridDim.x * 256) {
    int row = idx / 12, p = idx % 12;
    float v[8];
    if (p < 4) {
      const float* s = up_raw + (size_t)row * 32 + p * 8;
      int c0 = p * 8;
      #pragma unroll
      for (int j = 0; j < 8; ++j) v[j] = fmaxf(s[j] * sb[c0 + j] + sb[32 + c0 + j], 0.f);
    } else if (p < 8) {
      const float* s = x2 + (size_t)row * 32 + (p - 4) * 8;
      #pragma unroll
      for (int j = 0; j < 8; ++j) v[j] = s[j];
    } else {
      const float* s = x3 + (size_t)row * 32 + (p - 8) * 8;
      #pragma unroll
      for (int j = 0; j < 8; ++j) v[j] = s[j];
    }
    unsigned short o[8];
    #pragma unroll
    for (int j = 0; j < 8; ++j) o[j] = f2bf(v[j]);
    ((uint4*)xb)[idx] = *(uint4*)o;
  }
}

// ---------------- SubM conv: 2-phase pipelined, A->regs, B->LDS via global_load_lds ----------------
template <int CIN, bool SWZ, bool OUTBF>
__global__ __launch_bounds__(256) void conv_kernel(const unsigned short* __restrict__ feats,
                                                   const unsigned short* __restrict__ Wt,
                                                   const int* __restrict__ nbr,
                                                   const unsigned short* __restrict__ zp,
                                                   void* __restrict__ yout,
                                                   float* __restrict__ part1,
                                                   float* __restrict__ part2,
                                                   int N) {
  constexpr int KS = CIN / 32;        // MFMA K-steps per tap
  constexpr int TS = 64 * CIN;        // B tile elems
  constexpr int CPT = (TS / 8) / 256; // 16B chunks per thread for staging
  __shared__ unsigned short Bl[2 * TS];
  __shared__ float wsum[4][32];
  __shared__ float wsq[4][32];

  const int tid = threadIdx.x;
  const int wv = tid >> 6;
  const int lane = tid & 63;
  const int lr = lane & 15;
  const int lg = lane >> 4;
  const int wr = wv & 1;
  const int wc = wv >> 1;

  // XCD-aware bijective block remap (T1)
  int nwg = gridDim.x, orig = blockIdx.x;
  int qq = nwg >> 3, rr = nwg & 7, xcd = orig & 7, jj = orig >> 3;
  int bid = (xcd < rr ? xcd * (qq + 1) : rr * (qq + 1) + (xcd - rr) * qq) + jj;
  const int base = bid * 64;

  const int row0 = base + wr * 32 + lr;
  const int row1 = row0 + 16;

  floatx4 acc[2][2];
  #pragma unroll
  for (int m = 0; m < 2; ++m)
    #pragma unroll
    for (int ct = 0; ct < 2; ++ct) acc[m][ct] = (floatx4){0.f, 0.f, 0.f, 0.f};

  auto ldnbr = [&](int t, int* nb) {
    int tt = t > 26 ? 26 : t;
    nb[0] = (row0 < N) ? nbr[(size_t)row0 * 27 + tt] : -1;
    nb[1] = (row1 < N) ? nbr[(size_t)row1 * 27 + tt] : -1;
  };
  auto gather = [&](const int* nb, short8* A) {
    #pragma unroll
    for (int m = 0; m < 2; ++m) {
      const unsigned short* src = (nb[m] >= 0) ? (feats + (size_t)nb[m] * CIN) : zp;
      #pragma unroll
      for (int s = 0; s < KS; ++s) A[m * KS + s] = *(const short8*)(src + s * 32 + lg * 8);
    }
  };
  auto stageB = [&](int t, int bufi) {
    const unsigned short* src = Wt + (size_t)t * TS;
    #pragma unroll
    for (int i = 0; i < CPT; ++i) {
      int wchunk = i * 256 + wv * 64;  // wave-uniform first chunk
      GLL16(src + (size_t)(wchunk + lane) * 8, &Bl[(size_t)bufi * TS + (size_t)wchunk * 8]);
    }
  };
  auto compute = [&](const short8* A, int bufi) {
    const unsigned short* bb = &Bl[(size_t)bufi * TS];
    #pragma unroll
    for (int s = 0; s < KS; ++s) {
      short8 bfrag[2];
      #pragma unroll
      for (int ct = 0; ct < 2; ++ct) {
        int col = wc * 32 + ct * 16 + lr;
        int off;
        if (SWZ) {
          int c0 = s * 4 + lg;
          off = col * CIN + (((c0 ^ (col & 7)) << 3));
        } else {
          off = col * CIN + s * 32 + lg * 8;
        }
        bfrag[ct] = *(const short8*)(bb + off);
      }
      #pragma unroll
      for (int m = 0; m < 2; ++m)
        #pragma unroll
        for (int ct = 0; ct < 2; ++ct)
          acc[m][ct] = __builtin_amdgcn_mfma_f32_16x16x32_bf16(A[m * KS + s], bfrag[ct], acc[m][ct], 0, 0, 0);
    }
  };

  int nb0[2], nb1[2];
  short8 A0[2 * KS], A1[2 * KS];

  // prologue
  ldnbr(0, nb0);
  stageB(0, 0);
  gather(nb0, A0);
  ldnbr(1, nb1);
  __syncthreads();  // drains stageB(0)

  #pragma unroll 1
  for (int t = 0; t < 26; t += 2) {
    // even phase: compute tap t (buf0, A0); prefetch t+1
    stageB(t + 1, 1);
    gather(nb1, A1);
    ldnbr(t + 2, nb0);
    compute(A0, 0);
    __syncthreads();
    // odd phase: compute tap t+1 (buf1, A1); prefetch t+2
    stageB(t + 2, 0);
    gather(nb0, A0);
    ldnbr(t + 3, nb1);
    compute(A1, 1);
    __syncthreads();
  }
  compute(A0, 0);  // tap 26

  // epilogue: store + BN partials
  float cs[2], cq[2];
  cs[0] = cs[1] = cq[0] = cq[1] = 0.f;
  #pragma unroll
  for (int m = 0; m < 2; ++m) {
    #pragma unroll
    for (int ct = 0; ct < 2; ++ct) {
      #pragma unroll
      for (int reg = 0; reg < 4; ++reg) {
        float v = acc[m][ct][reg];
        int r = base + wr * 32 + m * 16 + lg * 4 + reg;
        int col = wc * 32 + ct * 16 + lr;
        if (r < N) {
          if (OUTBF)
            ((unsigned short*)yout)[(size_t)r * 64 + col] = f2bf(v);
          else
            ((float*)yout)[(size_t)r * 64 + col] = v;
        }
        cs[ct] += v;
        cq[ct] += v * v;
      }
    }
  }
  #pragma unroll
  for (int ct = 0; ct < 2; ++ct) {
    float a = cs[ct], b = cq[ct];
    a += __shfl_xor(a, 16);
    a += __shfl_xor(a, 32);
    b += __shfl_xor(b, 16);
    b += __shfl_xor(b, 32);
    if (lg == 0) {
      wsum[wv][ct * 16 + lr] = a;
      wsq[wv][ct * 16 + lr] = b;
    }
  }
  __syncthreads();
  if (tid < 64) {
    int wcol = tid >> 5, cidx = tid & 31;
    float s1 = wsum[wcol * 2 + 0][cidx] + wsum[wcol * 2 + 1][cidx];
    float s2 = wsq[wcol * 2 + 0][cidx] + wsq[wcol * 2 + 1][cidx];
    part1[(size_t)blockIdx.x * 64 + tid] = s1;
    part2[(size_t)blockIdx.x * 64 + tid] = s2;
  }
}

// ---------------- Apply BN+ReLU in place on bf16 (8 ch / thread) ----------------
__global__ __launch_bounds__(256) void apply_bn_bf16_inplace(unsigned short* __restrict__ y,
                                                             const float* __restrict__ sb,
                                                             int N) {
  int total = N * 8;
  for (int idx = blockIdx.x * 256 + threadIdx.x; idx < total; idx += gridDim.x * 256) {
    int c0 = (idx & 7) * 8;
    uint4 d = ((uint4*)y)[idx];
    unsigned short* u = (unsigned short*)&d;
    #pragma unroll
    for (int j = 0; j < 8; ++j) {
      float f = bf2f(u[j]);
      f = fmaxf(f * sb[c0 + j] + sb[64 + c0 + j], 0.f);
      u[j] = f2bf(f);
    }
    ((uint4*)y)[idx] = d;
  }
}

// ---------------- Apply BN+ReLU in place, fp32 (float4 / thread) ----------------
__global__ __launch_bounds__(256) void apply_bn_inplace(float* __restrict__ y,
                                                        const float* __restrict__ sb,
                                                        int N) {
  int total = N * 16;
  for (int idx = blockIdx.x * 256 + threadIdx.x; idx < total; idx += gridDim.x * 256) {
    int c0 = (idx & 15) * 4;
    float4 d = ((float4*)y)[idx];
    d.x = fmaxf(d.x * sb[c0 + 0] + sb[64 + c0 + 0], 0.f);
    d.y = fmaxf(d.y * sb[c0 + 1] + sb[64 + c0 + 1], 0.f);
    d.z = fmaxf(d.z * sb[c0 + 2] + sb[64 + c0 + 2], 0.f);
    d.w = fmaxf(d.w * sb[c0 + 3] + sb[64 + c0 + 3], 0.f);
    ((float4*)y)[idx] = d;
  }
}

extern "C" void kernel_launch(void* const* d_in, const int* in_sizes, int n_in,
                              void* d_out, int out_size, void* d_ws, size_t ws_size,
                              hipStream_t stream) {
  const float* x1 = (const float*)d_in[0];
  const float* x2 = (const float*)d_in[1];
  const float* x3 = (const float*)d_in[2];
  const float* Wup = (const float*)d_in[3];
  const float* gup = (const float*)d_in[4];
  const float* bup = (const float*)d_in[5];
  const float* W1 = (const float*)d_in[6];
  const float* g1 = (const float*)d_in[7];
  const float* b1 = (const float*)d_in[8];
  const float* W2 = (const float*)d_in[9];
  const float* g2 = (const float*)d_in[10];
  const float* b2 = (const float*)d_in[11];
  const int* up_src = (const int*)d_in[12];
  const int* up_off = (const int*)d_in[13];
  const int* nbr = (const int*)d_in[14];

  const int N = in_sizes[12];
  const int NB = (N + 63) / 64;

  char* ws = (char*)d_ws;
  size_t off = 0;
  auto alloc = [&](size_t bytes) -> void* {
    void* p = ws + off;
    off = (off + bytes + 255) & ~(size_t)255;
    return p;
  };

  unsigned short* xb   = (unsigned short*)alloc((size_t)N * 96 * 2);
  unsigned short* y1b  = (unsigned short*)alloc((size_t)N * 64 * 2);
  float* up_raw        = (float*)alloc((size_t)N * 32 * 4);
  unsigned short* W1t  = (unsigned short*)alloc((size_t)27 * 64 * 96 * 2);
  unsigned short* W2t  = (unsigned short*)alloc((size_t)27 * 64 * 64 * 2);
  unsigned short* zp   = (unsigned short*)alloc(256);
  float* upP1          = (float*)alloc((size_t)1024 * 32 * 4);
  float* upP2          = (float*)alloc((size_t)1024 * 32 * 4);
  float* c1P1          = (float*)alloc((size_t)NB * 64 * 4);
  float* c1P2          = (float*)alloc((size_t)NB * 64 * 4);
  float* c2P1          = (float*)alloc((size_t)NB * 64 * 4);
  float* c2P2          = (float*)alloc((size_t)NB * 64 * 4);
  float* sbup          = (float*)alloc(64 * 4);
  float* sb1           = (float*)alloc(128 * 4);
  float* sb2           = (float*)alloc(128 * 4);
  (void)ws_size;

  float* out = (float*)d_out;

  // 1. W -> bf16 (W1t linear, W2t chunk-swizzled) + zeropage
  convw_kernel<<<1081, 256, 0, stream>>>(W1, W2, W1t, W2t, zp);
  // 2. upsample
  up_kernel<<<1024, 256, 0, stream>>>(x1, up_src, up_off, Wup, up_raw, upP1, upP2, N);
  // 3. BN(up) finalize
  bn_finalize<32><<<1, 1024, 0, stream>>>(upP1, upP2, 1024, gup, bup, sbup, N);
  // 4. concat -> bf16
  concat_kernel<<<2048, 256, 0, stream>>>(up_raw, x2, x3, sbup, xb, N);
  // 5. conv1 (raw bf16 out into y1b)
  conv_kernel<96, false, true><<<NB, 256, 0, stream>>>(xb, W1t, nbr, zp, y1b, c1P1, c1P2, N);
  // 6. BN1 finalize
  bn_finalize<64><<<1, 1024, 0, stream>>>(c1P1, c1P2, NB, g1, b1, sb1, N);
  // 7. apply BN1 in place on bf16
  apply_bn_bf16_inplace<<<2048, 256, 0, stream>>>(y1b, sb1, N);
  // 8. conv2 (raw fp32 out into d_out)
  conv_kernel<64, true, false><<<NB, 256, 0, stream>>>(y1b, W2t, nbr, zp, out, c2P1, c2P2, N);
  // 9. BN2 finalize
  bn_finalize<64><<<1, 1024, 0, stream>>>(c2P1, c2P2, NB, g2, b2, sb2, N);
  // 10. apply BN2 in place (fp32)
  apply_bn_inplace<<<2048, 256, 0, stream>>>(out, sb2, N);
}

// Round 4
// 638.542 us; speedup vs baseline: 3.9840x; 1.2062x over previous
//
#include <hip/hip_runtime.h>

typedef __attribute__((ext_vector_type(8))) short short8;
typedef __attribute__((ext_vector_type(4))) float floatx4;

__device__ inline unsigned short f2bf(float f) {
  union { float f; unsigned u; } x; x.f = f;
  unsigned r = x.u + 0x7FFFu + ((x.u >> 16) & 1u);
  return (unsigned short)(r >> 16);
}
__device__ inline float bf2f(unsigned short h) {
  union { unsigned u; float f; } x; x.u = ((unsigned)h) << 16;
  return x.f;
}

#define GLL16(g, l)                                                  \
  __builtin_amdgcn_global_load_lds(                                  \
      (const __attribute__((address_space(1))) void*)(g),            \
      (__attribute__((address_space(3))) void*)(l), 16, 0, 0)

// ---------------- W transpose + bf16 convert (+ zeropage + Wup^T) ----------------
// W1t[k][c][q] linear; W2t[k][c][*] chunk-XOR swizzled; Wupt[k][c][q] = Wup[k][q][c]
__global__ __launch_bounds__(256) void convw_kernel(const float* __restrict__ W1,
                                                    const float* __restrict__ W2,
                                                    const float* __restrict__ Wup,
                                                    unsigned short* __restrict__ W1t,
                                                    unsigned short* __restrict__ W2t,
                                                    unsigned short* __restrict__ Wupt,
                                                    unsigned short* __restrict__ zp) {
  int idx = blockIdx.x * 256 + threadIdx.x;
  const int n1 = 27 * 96 * 64;
  const int n2 = 27 * 64 * 64;
  const int n3 = 8 * 32 * 96;
  if (idx < n1) {
    int k = idx / (96 * 64);
    int r = idx % (96 * 64);
    int q = r / 64, c = r % 64;
    W1t[((size_t)k * 64 + c) * 96 + q] = f2bf(W1[idx]);
  } else if (idx < n1 + n2) {
    int j = idx - n1;
    int k = j / 4096;
    int r = j % 4096;
    int q = r / 64, c = r % 64;
    int qs = (((q >> 3) ^ (c & 7)) << 3) | (q & 7);
    W2t[((size_t)k * 64 + c) * 64 + qs] = f2bf(W2[j]);
  } else if (idx < n1 + n2 + n3) {
    int o = idx - n1 - n2;
    int k = o / 3072;
    int r = o % 3072;
    int c = r / 96, q = r % 96;
    Wupt[o] = f2bf(Wup[((size_t)k * 96 + q) * 32 + c]);
  } else if (idx < n1 + n2 + n3 + 128) {
    zp[idx - n1 - n2 - n3] = 0;
  }
}

// ---------------- Upsample via masked 8-tap MFMA ----------------
// up[i] = x1[src[i]] @ Wup[off[i]] : per tap k, A-row masked by (off==k).
__global__ __launch_bounds__(256) void up_mfma_kernel(const float* __restrict__ x1,
                                                      const int* __restrict__ up_src,
                                                      const int* __restrict__ up_off,
                                                      const unsigned short* __restrict__ Wupt,
                                                      float* __restrict__ up_raw,
                                                      float* __restrict__ part1,
                                                      float* __restrict__ part2,
                                                      int N) {
  constexpr int PAD = 104;  // 96 + 8, keeps 16B alignment, ~2-way banks
  __shared__ unsigned short Wl[8 * 32 * PAD];
  __shared__ float wsum[4][32];
  __shared__ float wsq[4][32];

  const int tid = threadIdx.x;
  const int wv = tid >> 6;
  const int lane = tid & 63;
  const int lr = lane & 15;
  const int lg = lane >> 4;

  // stage all 8 Wup^T into LDS once: [k][c][q] -> [k][c][PAD]
  for (int ch = tid; ch < 8 * 32 * 12; ch += 256) {
    int kc = ch / 12, j = ch % 12;
    short8 v = *(const short8*)(Wupt + (size_t)kc * 96 + j * 8);
    *(short8*)(&Wl[kc * PAD + j * 8]) = v;
  }
  __syncthreads();

  const int nTiles = (N + 63) >> 6;
  const short8 z8 = {0, 0, 0, 0, 0, 0, 0, 0};
  float cs[2] = {0.f, 0.f}, cq[2] = {0.f, 0.f};

  for (int tile = blockIdx.x; tile < nTiles; tile += gridDim.x) {
    const int base = tile * 64;
    const int r = base + wv * 16 + lr;  // this lane's A-row
    int o = -100;
    const float* ptr = x1;
    if (r < N) {
      o = up_off[r];
      ptr = x1 + (size_t)up_src[r] * 96;
    }
    // gather row r, k-chunks lg*8 within each 32-wide k-step; convert to bf16
    short8 a_all[3];
    #pragma unroll
    for (int s = 0; s < 3; ++s) {
      float4 f0 = *(const float4*)(ptr + s * 32 + lg * 8);
      float4 f1 = *(const float4*)(ptr + s * 32 + lg * 8 + 4);
      unsigned short u[8];
      u[0] = f2bf(f0.x); u[1] = f2bf(f0.y); u[2] = f2bf(f0.z); u[3] = f2bf(f0.w);
      u[4] = f2bf(f1.x); u[5] = f2bf(f1.y); u[6] = f2bf(f1.z); u[7] = f2bf(f1.w);
      a_all[s] = *(short8*)u;
    }
    if (r >= N) {
      #pragma unroll
      for (int s = 0; s < 3; ++s) a_all[s] = z8;
    }

    floatx4 acc[2];
    acc[0] = (floatx4){0.f, 0.f, 0.f, 0.f};
    acc[1] = (floatx4){0.f, 0.f, 0.f, 0.f};
    #pragma unroll
    for (int k = 0; k < 8; ++k) {
      bool sel = (o == k);
      #pragma unroll
      for (int s = 0; s < 3; ++s) {
        short8 af = sel ? a_all[s] : z8;
        #pragma unroll
        for (int ct = 0; ct < 2; ++ct) {
          short8 bf = *(const short8*)(&Wl[(k * 32 + ct * 16 + lr) * PAD + s * 32 + lg * 8]);
          acc[ct] = __builtin_amdgcn_mfma_f32_16x16x32_bf16(af, bf, acc[ct], 0, 0, 0);
        }
      }
    }
    // store + BN partial accumulate (C row = base+wv*16+lg*4+reg, col = ct*16+lr)
    #pragma unroll
    for (int ct = 0; ct < 2; ++ct) {
      #pragma unroll
      for (int reg = 0; reg < 4; ++reg) {
        float v = acc[ct][reg];
        int r2 = base + wv * 16 + lg * 4 + reg;
        if (r2 < N) up_raw[(size_t)r2 * 32 + ct * 16 + lr] = v;
        cs[ct] += v;
        cq[ct] += v * v;
      }
    }
  }

  // final cross-lane + cross-wave partial reduction
  #pragma unroll
  for (int ct = 0; ct < 2; ++ct) {
    float a = cs[ct], b = cq[ct];
    a += __shfl_xor(a, 16);
    a += __shfl_xor(a, 32);
    b += __shfl_xor(b, 16);
    b += __shfl_xor(b, 32);
    if (lg == 0) {
      wsum[wv][ct * 16 + lr] = a;
      wsq[wv][ct * 16 + lr] = b;
    }
  }
  __syncthreads();
  if (tid < 32) {
    float s1 = wsum[0][tid] + wsum[1][tid] + wsum[2][tid] + wsum[3][tid];
    float s2 = wsq[0][tid] + wsq[1][tid] + wsq[2][tid] + wsq[3][tid];
    part1[(size_t)blockIdx.x * 32 + tid] = s1;
    part2[(size_t)blockIdx.x * 32 + tid] = s2;
  }
}

// ---------------- BN finalize (parallel reduce) ----------------
template <int C>
__global__ __launch_bounds__(1024) void bn_finalize(const float* __restrict__ part1,
                                                    const float* __restrict__ part2,
                                                    int nP, const float* __restrict__ g,
                                                    const float* __restrict__ b,
                                                    float* __restrict__ sb, int N) {
  constexpr int R = 1024 / C;
  __shared__ float red1[1024];
  __shared__ float red2[1024];
  const int tid = threadIdx.x;
  const int c = tid % C;
  const int r = tid / C;
  float s1 = 0.f, s2 = 0.f;
  for (int p = r; p < nP; p += R) {
    s1 += part1[(size_t)p * C + c];
    s2 += part2[(size_t)p * C + c];
  }
  red1[tid] = s1;
  red2[tid] = s2;
  __syncthreads();
  #pragma unroll
  for (int step = R / 2; step > 0; step >>= 1) {
    if (r < step) {
      red1[tid] += red1[tid + step * C];
      red2[tid] += red2[tid + step * C];
    }
    __syncthreads();
  }
  if (r == 0) {
    float mean = red1[c] / (float)N;
    float var = red2[c] / (float)N - mean * mean;
    float sc = g[c] * rsqrtf(var + 1e-5f);
    sb[c] = sc;
    sb[C + c] = b[c] - mean * sc;
  }
}

// ---------------- Concat (vectorized, 8 ch / thread) ----------------
__global__ __launch_bounds__(256) void concat_kernel(const float* __restrict__ up_raw,
                                                     const float* __restrict__ x2,
                                                     const float* __restrict__ x3,
                                                     const float* __restrict__ sb,
                                                     unsigned short* __restrict__ xb,
                                                     int N) {
  int total = N * 12;
  for (int idx = blockIdx.x * 256 + threadIdx.x; idx < total; idx += gridDim.x * 256) {
    int row = idx / 12, p = idx % 12;
    float v[8];
    if (p < 4) {
      const float* s = up_raw + (size_t)row * 32 + p * 8;
      int c0 = p * 8;
      #pragma unroll
      for (int j = 0; j < 8; ++j) v[j] = fmaxf(s[j] * sb[c0 + j] + sb[32 + c0 + j], 0.f);
    } else if (p < 8) {
      const float* s = x2 + (size_t)row * 32 + (p - 4) * 8;
      #pragma unroll
      for (int j = 0; j < 8; ++j) v[j] = s[j];
    } else {
      const float* s = x3 + (size_t)row * 32 + (p - 8) * 8;
      #pragma unroll
      for (int j = 0; j < 8; ++j) v[j] = s[j];
    }
    unsigned short o[8];
    #pragma unroll
    for (int j = 0; j < 8; ++j) o[j] = f2bf(v[j]);
    ((uint4*)xb)[idx] = *(uint4*)o;
  }
}

// ---------------- SubM conv: 2-phase pipelined, A->regs, B->LDS via global_load_lds ----------------
template <int CIN, bool SWZ, bool OUTBF>
__global__ __launch_bounds__(256) void conv_kernel(const unsigned short* __restrict__ feats,
                                                   const unsigned short* __restrict__ Wt,
                                                   const int* __restrict__ nbr,
                                                   const unsigned short* __restrict__ zp,
                                                   void* __restrict__ yout,
                                                   float* __restrict__ part1,
                                                   float* __restrict__ part2,
                                                   int N) {
  constexpr int KS = CIN / 32;        // MFMA K-steps per tap
  constexpr int TS = 64 * CIN;        // B tile elems
  constexpr int CPT = (TS / 8) / 256; // 16B chunks per thread for staging
  __shared__ unsigned short Bl[2 * TS];
  __shared__ float wsum[4][32];
  __shared__ float wsq[4][32];

  const int tid = threadIdx.x;
  const int wv = tid >> 6;
  const int lane = tid & 63;
  const int lr = lane & 15;
  const int lg = lane >> 4;
  const int wr = wv & 1;
  const int wc = wv >> 1;

  // XCD-aware bijective block remap (T1)
  int nwg = gridDim.x, orig = blockIdx.x;
  int qq = nwg >> 3, rr = nwg & 7, xcd = orig & 7, jj = orig >> 3;
  int bid = (xcd < rr ? xcd * (qq + 1) : rr * (qq + 1) + (xcd - rr) * qq) + jj;
  const int base = bid * 64;

  const int row0 = base + wr * 32 + lr;
  const int row1 = row0 + 16;

  floatx4 acc[2][2];
  #pragma unroll
  for (int m = 0; m < 2; ++m)
    #pragma unroll
    for (int ct = 0; ct < 2; ++ct) acc[m][ct] = (floatx4){0.f, 0.f, 0.f, 0.f};

  auto ldnbr = [&](int t, int* nb) {
    int tt = t > 26 ? 26 : t;
    nb[0] = (row0 < N) ? nbr[(size_t)row0 * 27 + tt] : -1;
    nb[1] = (row1 < N) ? nbr[(size_t)row1 * 27 + tt] : -1;
  };
  auto gather = [&](const int* nb, short8* A) {
    #pragma unroll
    for (int m = 0; m < 2; ++m) {
      const unsigned short* src = (nb[m] >= 0) ? (feats + (size_t)nb[m] * CIN) : zp;
      #pragma unroll
      for (int s = 0; s < KS; ++s) A[m * KS + s] = *(const short8*)(src + s * 32 + lg * 8);
    }
  };
  auto stageB = [&](int t, int bufi) {
    const unsigned short* src = Wt + (size_t)t * TS;
    #pragma unroll
    for (int i = 0; i < CPT; ++i) {
      int wchunk = i * 256 + wv * 64;  // wave-uniform first chunk
      GLL16(src + (size_t)(wchunk + lane) * 8, &Bl[(size_t)bufi * TS + (size_t)wchunk * 8]);
    }
  };
  auto compute = [&](const short8* A, int bufi) {
    const unsigned short* bb = &Bl[(size_t)bufi * TS];
    #pragma unroll
    for (int s = 0; s < KS; ++s) {
      short8 bfrag[2];
      #pragma unroll
      for (int ct = 0; ct < 2; ++ct) {
        int col = wc * 32 + ct * 16 + lr;
        int off;
        if (SWZ) {
          int c0 = s * 4 + lg;
          off = col * CIN + (((c0 ^ (col & 7)) << 3));
        } else {
          off = col * CIN + s * 32 + lg * 8;
        }
        bfrag[ct] = *(const short8*)(bb + off);
      }
      #pragma unroll
      for (int m = 0; m < 2; ++m)
        #pragma unroll
        for (int ct = 0; ct < 2; ++ct)
          acc[m][ct] = __builtin_amdgcn_mfma_f32_16x16x32_bf16(A[m * KS + s], bfrag[ct], acc[m][ct], 0, 0, 0);
    }
  };

  int nb0[2], nb1[2];
  short8 A0[2 * KS], A1[2 * KS];

  // prologue
  ldnbr(0, nb0);
  stageB(0, 0);
  gather(nb0, A0);
  ldnbr(1, nb1);
  __syncthreads();  // drains stageB(0)

  #pragma unroll 1
  for (int t = 0; t < 26; t += 2) {
    // even phase: compute tap t (buf0, A0); prefetch t+1
    stageB(t + 1, 1);
    gather(nb1, A1);
    ldnbr(t + 2, nb0);
    compute(A0, 0);
    __syncthreads();
    // odd phase: compute tap t+1 (buf1, A1); prefetch t+2
    stageB(t + 2, 0);
    gather(nb0, A0);
    ldnbr(t + 3, nb1);
    compute(A1, 1);
    __syncthreads();
  }
  compute(A0, 0);  // tap 26

  // epilogue: store + BN partials
  float cs[2], cq[2];
  cs[0] = cs[1] = cq[0] = cq[1] = 0.f;
  #pragma unroll
  for (int m = 0; m < 2; ++m) {
    #pragma unroll
    for (int ct = 0; ct < 2; ++ct) {
      #pragma unroll
      for (int reg = 0; reg < 4; ++reg) {
        float v = acc[m][ct][reg];
        int r = base + wr * 32 + m * 16 + lg * 4 + reg;
        int col = wc * 32 + ct * 16 + lr;
        if (r < N) {
          if (OUTBF)
            ((unsigned short*)yout)[(size_t)r * 64 + col] = f2bf(v);
          else
            ((float*)yout)[(size_t)r * 64 + col] = v;
        }
        cs[ct] += v;
        cq[ct] += v * v;
      }
    }
  }
  #pragma unroll
  for (int ct = 0; ct < 2; ++ct) {
    float a = cs[ct], b = cq[ct];
    a += __shfl_xor(a, 16);
    a += __shfl_xor(a, 32);
    b += __shfl_xor(b, 16);
    b += __shfl_xor(b, 32);
    if (lg == 0) {
      wsum[wv][ct * 16 + lr] = a;
      wsq[wv][ct * 16 + lr] = b;
    }
  }
  __syncthreads();
  if (tid < 64) {
    int wcol = tid >> 5, cidx = tid & 31;
    float s1 = wsum[wcol * 2 + 0][cidx] + wsum[wcol * 2 + 1][cidx];
    float s2 = wsq[wcol * 2 + 0][cidx] + wsq[wcol * 2 + 1][cidx];
    part1[(size_t)blockIdx.x * 64 + tid] = s1;
    part2[(size_t)blockIdx.x * 64 + tid] = s2;
  }
}

// ---------------- Apply BN+ReLU in place on bf16 (8 ch / thread) ----------------
__global__ __launch_bounds__(256) void apply_bn_bf16_inplace(unsigned short* __restrict__ y,
                                                             const float* __restrict__ sb,
                                                             int N) {
  int total = N * 8;
  for (int idx = blockIdx.x * 256 + threadIdx.x; idx < total; idx += gridDim.x * 256) {
    int c0 = (idx & 7) * 8;
    uint4 d = ((uint4*)y)[idx];
    unsigned short* u = (unsigned short*)&d;
    #pragma unroll
    for (int j = 0; j < 8; ++j) {
      float f = bf2f(u[j]);
      f = fmaxf(f * sb[c0 + j] + sb[64 + c0 + j], 0.f);
      u[j] = f2bf(f);
    }
    ((uint4*)y)[idx] = d;
  }
}

// ---------------- Apply BN+ReLU in place, fp32 (float4 / thread) ----------------
__global__ __launch_bounds__(256) void apply_bn_inplace(float* __restrict__ y,
                                                        const float* __restrict__ sb,
                                                        int N) {
  int total = N * 16;
  for (int idx = blockIdx.x * 256 + threadIdx.x; idx < total; idx += gridDim.x * 256) {
    int c0 = (idx & 15) * 4;
    float4 d = ((float4*)y)[idx];
    d.x = fmaxf(d.x * sb[c0 + 0] + sb[64 + c0 + 0], 0.f);
    d.y = fmaxf(d.y * sb[c0 + 1] + sb[64 + c0 + 1], 0.f);
    d.z = fmaxf(d.z * sb[c0 + 2] + sb[64 + c0 + 2], 0.f);
    d.w = fmaxf(d.w * sb[c0 + 3] + sb[64 + c0 + 3], 0.f);
    ((float4*)y)[idx] = d;
  }
}

extern "C" void kernel_launch(void* const* d_in, const int* in_sizes, int n_in,
                              void* d_out, int out_size, void* d_ws, size_t ws_size,
                              hipStream_t stream) {
  const float* x1 = (const float*)d_in[0];
  const float* x2 = (const float*)d_in[1];
  const float* x3 = (const float*)d_in[2];
  const float* Wup = (const float*)d_in[3];
  const float* gup = (const float*)d_in[4];
  const float* bup = (const float*)d_in[5];
  const float* W1 = (const float*)d_in[6];
  const float* g1 = (const float*)d_in[7];
  const float* b1 = (const float*)d_in[8];
  const float* W2 = (const float*)d_in[9];
  const float* g2 = (const float*)d_in[10];
  const float* b2 = (const float*)d_in[11];
  const int* up_src = (const int*)d_in[12];
  const int* up_off = (const int*)d_in[13];
  const int* nbr = (const int*)d_in[14];

  const int N = in_sizes[12];
  const int NB = (N + 63) / 64;

  char* ws = (char*)d_ws;
  size_t off = 0;
  auto alloc = [&](size_t bytes) -> void* {
    void* p = ws + off;
    off = (off + bytes + 255) & ~(size_t)255;
    return p;
  };

  unsigned short* xb   = (unsigned short*)alloc((size_t)N * 96 * 2);
  unsigned short* y1b  = (unsigned short*)alloc((size_t)N * 64 * 2);
  float* up_raw        = (float*)alloc((size_t)N * 32 * 4);
  unsigned short* W1t  = (unsigned short*)alloc((size_t)27 * 64 * 96 * 2);
  unsigned short* W2t  = (unsigned short*)alloc((size_t)27 * 64 * 64 * 2);
  unsigned short* Wupt = (unsigned short*)alloc((size_t)8 * 32 * 96 * 2);
  unsigned short* zp   = (unsigned short*)alloc(256);
  float* upP1          = (float*)alloc((size_t)1024 * 32 * 4);
  float* upP2          = (float*)alloc((size_t)1024 * 32 * 4);
  float* c1P1          = (float*)alloc((size_t)NB * 64 * 4);
  float* c1P2          = (float*)alloc((size_t)NB * 64 * 4);
  float* c2P1          = (float*)alloc((size_t)NB * 64 * 4);
  float* c2P2          = (float*)alloc((size_t)NB * 64 * 4);
  float* sbup          = (float*)alloc(64 * 4);
  float* sb1           = (float*)alloc(128 * 4);
  float* sb2           = (float*)alloc(128 * 4);
  (void)ws_size;

  float* out = (float*)d_out;

  // 1. W -> bf16 (W1t linear, W2t chunk-swizzled, Wup^T) + zeropage
  convw_kernel<<<1177, 256, 0, stream>>>(W1, W2, Wup, W1t, W2t, Wupt, zp);
  // 2. upsample (MFMA, masked 8-tap)
  up_mfma_kernel<<<1024, 256, 0, stream>>>(x1, up_src, up_off, Wupt, up_raw, upP1, upP2, N);
  // 3. BN(up) finalize
  bn_finalize<32><<<1, 1024, 0, stream>>>(upP1, upP2, 1024, gup, bup, sbup, N);
  // 4. concat -> bf16
  concat_kernel<<<2048, 256, 0, stream>>>(up_raw, x2, x3, sbup, xb, N);
  // 5. conv1 (raw bf16 out into y1b)
  conv_kernel<96, false, true><<<NB, 256, 0, stream>>>(xb, W1t, nbr, zp, y1b, c1P1, c1P2, N);
  // 6. BN1 finalize
  bn_finalize<64><<<1, 1024, 0, stream>>>(c1P1, c1P2, NB, g1, b1, sb1, N);
  // 7. apply BN1 in place on bf16
  apply_bn_bf16_inplace<<<2048, 256, 0, stream>>>(y1b, sb1, N);
  // 8. conv2 (raw fp32 out into d_out)
  conv_kernel<64, true, false><<<NB, 256, 0, stream>>>(y1b, W2t, nbr, zp, out, c2P1, c2P2, N);
  // 9. BN2 finalize
  bn_finalize<64><<<1, 1024, 0, stream>>>(c2P1, c2P2, NB, g2, b2, sb2, N);
  // 10. apply BN2 in place (fp32)
  apply_bn_inplace<<<2048, 256, 0, stream>>>(out, sb2, N);
}

// Round 5
// 598.257 us; speedup vs baseline: 4.2523x; 1.0673x over previous
//
#include <hip/hip_runtime.h>

typedef __attribute__((ext_vector_type(8))) short short8;
typedef __attribute__((ext_vector_type(4))) float floatx4;

__device__ inline unsigned short f2bf(float f) {
  union { float f; unsigned u; } x; x.f = f;
  unsigned r = x.u + 0x7FFFu + ((x.u >> 16) & 1u);
  return (unsigned short)(r >> 16);
}
__device__ inline float bf2f(unsigned short h) {
  union { unsigned u; float f; } x; x.u = ((unsigned)h) << 16;
  return x.f;
}

// ---------------- W -> bf16 (all linear [k][c][q]) + zero BN-partial buffers ----------------
__global__ __launch_bounds__(256) void convw_kernel(const float* __restrict__ W1,
                                                    const float* __restrict__ W2,
                                                    const float* __restrict__ Wup,
                                                    unsigned short* __restrict__ W1t,
                                                    unsigned short* __restrict__ W2t,
                                                    unsigned short* __restrict__ Wupt,
                                                    float* __restrict__ parts) {
  int idx = blockIdx.x * 256 + threadIdx.x;
  const int n1 = 27 * 96 * 64;
  const int n2 = 27 * 64 * 64;
  const int n3 = 8 * 32 * 96;
  if (idx < n1) {
    int k = idx / (96 * 64);
    int r = idx % (96 * 64);
    int q = r / 64, c = r % 64;
    W1t[((size_t)k * 64 + c) * 96 + q] = f2bf(W1[idx]);
  } else if (idx < n1 + n2) {
    int j = idx - n1;
    int k = j / 4096;
    int r = j % 4096;
    int q = r / 64, c = r % 64;
    W2t[((size_t)k * 64 + c) * 64 + q] = f2bf(W2[j]);
  } else if (idx < n1 + n2 + n3) {
    int o = idx - n1 - n2;
    int k = o / 3072;
    int r = o % 3072;
    int c = r / 96, q = r % 96;
    Wupt[o] = f2bf(Wup[((size_t)k * 96 + q) * 32 + c]);
  } else if (idx < n1 + n2 + n3 + 320) {
    parts[idx - n1 - n2 - n3] = 0.f;  // upP1(32) upP2(32) c1P1(64) c1P2(64) c2P1(64) c2P2(64)
  }
}

// ---------------- Upsample via masked 8-tap MFMA (atomic BN partials) ----------------
__global__ __launch_bounds__(256) void up_mfma_kernel(const float* __restrict__ x1,
                                                      const int* __restrict__ up_src,
                                                      const int* __restrict__ up_off,
                                                      const unsigned short* __restrict__ Wupt,
                                                      float* __restrict__ up_raw,
                                                      float* __restrict__ part1,
                                                      float* __restrict__ part2,
                                                      int N) {
  constexpr int PAD = 104;
  __shared__ unsigned short Wl[8 * 32 * PAD];
  __shared__ float wsum[4][32];
  __shared__ float wsq[4][32];

  const int tid = threadIdx.x;
  const int wv = tid >> 6;
  const int lane = tid & 63;
  const int lr = lane & 15;
  const int lg = lane >> 4;

  for (int ch = tid; ch < 8 * 32 * 12; ch += 256) {
    int kc = ch / 12, j = ch % 12;
    short8 v = *(const short8*)(Wupt + (size_t)kc * 96 + j * 8);
    *(short8*)(&Wl[kc * PAD + j * 8]) = v;
  }
  __syncthreads();

  const int nTiles = (N + 63) >> 6;
  const short8 z8 = {0, 0, 0, 0, 0, 0, 0, 0};
  float cs[2] = {0.f, 0.f}, cq[2] = {0.f, 0.f};

  for (int tile = blockIdx.x; tile < nTiles; tile += gridDim.x) {
    const int base = tile * 64;
    const int r = base + wv * 16 + lr;
    int o = -100;
    const float* ptr = x1;
    if (r < N) {
      o = up_off[r];
      ptr = x1 + (size_t)up_src[r] * 96;
    }
    short8 a_all[3];
    #pragma unroll
    for (int s = 0; s < 3; ++s) {
      float4 f0 = *(const float4*)(ptr + s * 32 + lg * 8);
      float4 f1 = *(const float4*)(ptr + s * 32 + lg * 8 + 4);
      unsigned short u[8];
      u[0] = f2bf(f0.x); u[1] = f2bf(f0.y); u[2] = f2bf(f0.z); u[3] = f2bf(f0.w);
      u[4] = f2bf(f1.x); u[5] = f2bf(f1.y); u[6] = f2bf(f1.z); u[7] = f2bf(f1.w);
      a_all[s] = *(short8*)u;
    }
    if (r >= N) {
      #pragma unroll
      for (int s = 0; s < 3; ++s) a_all[s] = z8;
    }

    floatx4 acc[2];
    acc[0] = (floatx4){0.f, 0.f, 0.f, 0.f};
    acc[1] = (floatx4){0.f, 0.f, 0.f, 0.f};
    #pragma unroll
    for (int k = 0; k < 8; ++k) {
      bool sel = (o == k);
      #pragma unroll
      for (int s = 0; s < 3; ++s) {
        short8 af = sel ? a_all[s] : z8;
        #pragma unroll
        for (int ct = 0; ct < 2; ++ct) {
          short8 bf = *(const short8*)(&Wl[(k * 32 + ct * 16 + lr) * PAD + s * 32 + lg * 8]);
          acc[ct] = __builtin_amdgcn_mfma_f32_16x16x32_bf16(af, bf, acc[ct], 0, 0, 0);
        }
      }
    }
    #pragma unroll
    for (int ct = 0; ct < 2; ++ct) {
      #pragma unroll
      for (int reg = 0; reg < 4; ++reg) {
        float v = acc[ct][reg];
        int r2 = base + wv * 16 + lg * 4 + reg;
        if (r2 < N) up_raw[(size_t)r2 * 32 + ct * 16 + lr] = v;
        cs[ct] += v;
        cq[ct] += v * v;
      }
    }
  }

  #pragma unroll
  for (int ct = 0; ct < 2; ++ct) {
    float a = cs[ct], b = cq[ct];
    a += __shfl_xor(a, 16);
    a += __shfl_xor(a, 32);
    b += __shfl_xor(b, 16);
    b += __shfl_xor(b, 32);
    if (lg == 0) {
      wsum[wv][ct * 16 + lr] = a;
      wsq[wv][ct * 16 + lr] = b;
    }
  }
  __syncthreads();
  if (tid < 32) {
    float s1 = wsum[0][tid] + wsum[1][tid] + wsum[2][tid] + wsum[3][tid];
    float s2 = wsq[0][tid] + wsq[1][tid] + wsq[2][tid] + wsq[3][tid];
    atomicAdd(&part1[tid], s1);
    atomicAdd(&part2[tid], s2);
  }
}

// ---------------- Concat (folds BN-up finalize) ----------------
__global__ __launch_bounds__(256) void concat_kernel(const float* __restrict__ up_raw,
                                                     const float* __restrict__ x2,
                                                     const float* __restrict__ x3,
                                                     const float* __restrict__ part1,
                                                     const float* __restrict__ part2,
                                                     const float* __restrict__ g,
                                                     const float* __restrict__ b,
                                                     unsigned short* __restrict__ xb,
                                                     int N) {
  __shared__ float ssb[64];
  if (threadIdx.x < 32) {
    int c = threadIdx.x;
    float mean = part1[c] / (float)N;
    float var = part2[c] / (float)N - mean * mean;
    float sc = g[c] * rsqrtf(var + 1e-5f);
    ssb[c] = sc;
    ssb[32 + c] = b[c] - mean * sc;
  }
  __syncthreads();
  int total = N * 12;
  for (int idx = blockIdx.x * 256 + threadIdx.x; idx < total; idx += gridDim.x * 256) {
    int row = idx / 12, p = idx % 12;
    float v[8];
    if (p < 4) {
      const float* s = up_raw + (size_t)row * 32 + p * 8;
      int c0 = p * 8;
      #pragma unroll
      for (int j = 0; j < 8; ++j) v[j] = fmaxf(s[j] * ssb[c0 + j] + ssb[32 + c0 + j], 0.f);
    } else if (p < 8) {
      const float* s = x2 + (size_t)row * 32 + (p - 4) * 8;
      #pragma unroll
      for (int j = 0; j < 8; ++j) v[j] = s[j];
    } else {
      const float* s = x3 + (size_t)row * 32 + (p - 8) * 8;
      #pragma unroll
      for (int j = 0; j < 8; ++j) v[j] = s[j];
    }
    unsigned short o[8];
    #pragma unroll
    for (int j = 0; j < 8; ++j) o[j] = f2bf(v[j]);
    ((uint4*)xb)[idx] = *(uint4*)o;
  }
}

// ---------------- SubM conv: barrier-free, A->regs predicated, B from global, valid-skip ----------------
// Block = 128 rows x 64 cols; wave(wr,wc) = rows [base+wr*64,+64) x cols [wc*32,+32).
template <int CIN, bool OUTBF>
__global__ __launch_bounds__(256) void conv_kernel(const unsigned short* __restrict__ feats,
                                                   const unsigned short* __restrict__ Wt,
                                                   const int* __restrict__ nbr,
                                                   void* __restrict__ yout,
                                                   float* __restrict__ part1,
                                                   float* __restrict__ part2,
                                                   int N) {
  constexpr int KS = CIN / 32;
  const int tid = threadIdx.x;
  const int wv = tid >> 6;
  const int lane = tid & 63;
  const int lr = lane & 15;
  const int lg = lane >> 4;
  const int wr = wv & 1;
  const int wc = wv >> 1;
  const int base = blockIdx.x * 128;
  const int rbase = base + wr * 64 + lr;
  const short8 z8 = {0, 0, 0, 0, 0, 0, 0, 0};

  floatx4 acc[4][2];
  #pragma unroll
  for (int m = 0; m < 4; ++m)
    #pragma unroll
    for (int ct = 0; ct < 2; ++ct) acc[m][ct] = (floatx4){0.f, 0.f, 0.f, 0.f};

  int nbc[4];
  #pragma unroll
  for (int m = 0; m < 4; ++m) {
    int r = rbase + m * 16;
    nbc[m] = (r < N) ? nbr[(size_t)r * 27] : -1;
  }

  #pragma unroll 1
  for (int t = 0; t < 27; ++t) {
    // prefetch next tap's neighbor indices (nbr row is L1-resident across taps)
    int nbn[4];
    int tn = (t < 26) ? t + 1 : 26;
    #pragma unroll
    for (int m = 0; m < 4; ++m) {
      int r = rbase + m * 16;
      nbn[m] = (r < N) ? nbr[(size_t)r * 27 + tn] : -1;
    }
    // A fragments: predicated gather (invalid lanes issue no loads)
    short8 A[4][KS];
    #pragma unroll
    for (int m = 0; m < 4; ++m) {
      #pragma unroll
      for (int s = 0; s < KS; ++s) A[m][s] = z8;
      if (nbc[m] >= 0) {
        const unsigned short* src = feats + (size_t)nbc[m] * CIN + lg * 8;
        #pragma unroll
        for (int s = 0; s < KS; ++s) A[m][s] = *(const short8*)(src + s * 32);
      }
    }
    bool any0 = __any(nbc[0] >= 0), any1 = __any(nbc[1] >= 0);
    bool any2 = __any(nbc[2] >= 0), any3 = __any(nbc[3] >= 0);
    if (any0 | any1 | any2 | any3) {
      // B fragments direct from global (L1/L2-resident 12KB tap slice)
      short8 B[2][KS];
      const unsigned short* wsrc = Wt + ((size_t)t * 64 + wc * 32 + lr) * CIN + lg * 8;
      #pragma unroll
      for (int ct = 0; ct < 2; ++ct)
        #pragma unroll
        for (int s = 0; s < KS; ++s)
          B[ct][s] = *(const short8*)(wsrc + ct * 16 * CIN + s * 32);
      #pragma unroll
      for (int m = 0; m < 4; ++m) {
        bool anym = (m == 0) ? any0 : (m == 1) ? any1 : (m == 2) ? any2 : any3;
        if (anym) {
          #pragma unroll
          for (int s = 0; s < KS; ++s) {
            acc[m][0] = __builtin_amdgcn_mfma_f32_16x16x32_bf16(A[m][s], B[0][s], acc[m][0], 0, 0, 0);
            acc[m][1] = __builtin_amdgcn_mfma_f32_16x16x32_bf16(A[m][s], B[1][s], acc[m][1], 0, 0, 0);
          }
        }
      }
    }
    #pragma unroll
    for (int m = 0; m < 4; ++m) nbc[m] = nbn[m];
  }

  // epilogue: store + atomic BN partials (no LDS, no barrier)
  float cs[2] = {0.f, 0.f}, cq[2] = {0.f, 0.f};
  #pragma unroll
  for (int m = 0; m < 4; ++m) {
    #pragma unroll
    for (int ct = 0; ct < 2; ++ct) {
      #pragma unroll
      for (int reg = 0; reg < 4; ++reg) {
        float v = acc[m][ct][reg];
        int r = base + wr * 64 + m * 16 + lg * 4 + reg;
        int col = wc * 32 + ct * 16 + lr;
        if (r < N) {
          if (OUTBF)
            ((unsigned short*)yout)[(size_t)r * 64 + col] = f2bf(v);
          else
            ((float*)yout)[(size_t)r * 64 + col] = v;
        }
        cs[ct] += v;
        cq[ct] += v * v;
      }
    }
  }
  #pragma unroll
  for (int ct = 0; ct < 2; ++ct) {
    float a = cs[ct], b = cq[ct];
    a += __shfl_xor(a, 16);
    a += __shfl_xor(a, 32);
    b += __shfl_xor(b, 16);
    b += __shfl_xor(b, 32);
    if (lane < 16) {
      atomicAdd(&part1[wc * 32 + ct * 16 + lr], a);
      atomicAdd(&part2[wc * 32 + ct * 16 + lr], b);
    }
  }
}

// ---------------- Apply BN+ReLU in place on bf16 (folds bn1 finalize) ----------------
__global__ __launch_bounds__(256) void apply_bn_bf16_inplace(unsigned short* __restrict__ y,
                                                             const float* __restrict__ part1,
                                                             const float* __restrict__ part2,
                                                             const float* __restrict__ g,
                                                             const float* __restrict__ b,
                                                             int N) {
  __shared__ float ssb[128];
  if (threadIdx.x < 64) {
    int c = threadIdx.x;
    float mean = part1[c] / (float)N;
    float var = part2[c] / (float)N - mean * mean;
    float sc = g[c] * rsqrtf(var + 1e-5f);
    ssb[c] = sc;
    ssb[64 + c] = b[c] - mean * sc;
  }
  __syncthreads();
  int total = N * 8;
  for (int idx = blockIdx.x * 256 + threadIdx.x; idx < total; idx += gridDim.x * 256) {
    int c0 = (idx & 7) * 8;
    uint4 d = ((uint4*)y)[idx];
    unsigned short* u = (unsigned short*)&d;
    #pragma unroll
    for (int j = 0; j < 8; ++j) {
      float f = bf2f(u[j]);
      f = fmaxf(f * ssb[c0 + j] + ssb[64 + c0 + j], 0.f);
      u[j] = f2bf(f);
    }
    ((uint4*)y)[idx] = d;
  }
}

// ---------------- Apply BN+ReLU in place, fp32 (folds bn2 finalize) ----------------
__global__ __launch_bounds__(256) void apply_bn_inplace(float* __restrict__ y,
                                                        const float* __restrict__ part1,
                                                        const float* __restrict__ part2,
                                                        const float* __restrict__ g,
                                                        const float* __restrict__ b,
                                                        int N) {
  __shared__ float ssb[128];
  if (threadIdx.x < 64) {
    int c = threadIdx.x;
    float mean = part1[c] / (float)N;
    float var = part2[c] / (float)N - mean * mean;
    float sc = g[c] * rsqrtf(var + 1e-5f);
    ssb[c] = sc;
    ssb[64 + c] = b[c] - mean * sc;
  }
  __syncthreads();
  int total = N * 16;
  for (int idx = blockIdx.x * 256 + threadIdx.x; idx < total; idx += gridDim.x * 256) {
    int c0 = (idx & 15) * 4;
    float4 d = ((float4*)y)[idx];
    d.x = fmaxf(d.x * ssb[c0 + 0] + ssb[64 + c0 + 0], 0.f);
    d.y = fmaxf(d.y * ssb[c0 + 1] + ssb[64 + c0 + 1], 0.f);
    d.z = fmaxf(d.z * ssb[c0 + 2] + ssb[64 + c0 + 2], 0.f);
    d.w = fmaxf(d.w * ssb[c0 + 3] + ssb[64 + c0 + 3], 0.f);
    ((float4*)y)[idx] = d;
  }
}

extern "C" void kernel_launch(void* const* d_in, const int* in_sizes, int n_in,
                              void* d_out, int out_size, void* d_ws, size_t ws_size,
                              hipStream_t stream) {
  const float* x1 = (const float*)d_in[0];
  const float* x2 = (const float*)d_in[1];
  const float* x3 = (const float*)d_in[2];
  const float* Wup = (const float*)d_in[3];
  const float* gup = (const float*)d_in[4];
  const float* bup = (const float*)d_in[5];
  const float* W1 = (const float*)d_in[6];
  const float* g1 = (const float*)d_in[7];
  const float* b1 = (const float*)d_in[8];
  const float* W2 = (const float*)d_in[9];
  const float* g2 = (const float*)d_in[10];
  const float* b2 = (const float*)d_in[11];
  const int* up_src = (const int*)d_in[12];
  const int* up_off = (const int*)d_in[13];
  const int* nbr = (const int*)d_in[14];

  const int N = in_sizes[12];
  const int NB2 = (N + 127) / 128;

  char* ws = (char*)d_ws;
  size_t off = 0;
  auto alloc = [&](size_t bytes) -> void* {
    void* p = ws + off;
    off = (off + bytes + 255) & ~(size_t)255;
    return p;
  };

  unsigned short* xb   = (unsigned short*)alloc((size_t)N * 96 * 2);
  unsigned short* y1b  = (unsigned short*)alloc((size_t)N * 64 * 2);
  float* up_raw        = (float*)alloc((size_t)N * 32 * 4);
  unsigned short* W1t  = (unsigned short*)alloc((size_t)27 * 64 * 96 * 2);
  unsigned short* W2t  = (unsigned short*)alloc((size_t)27 * 64 * 64 * 2);
  unsigned short* Wupt = (unsigned short*)alloc((size_t)8 * 32 * 96 * 2);
  float* parts         = (float*)alloc(320 * 4);
  (void)ws_size;

  float* upP1 = parts;
  float* upP2 = parts + 32;
  float* c1P1 = parts + 64;
  float* c1P2 = parts + 128;
  float* c2P1 = parts + 192;
  float* c2P2 = parts + 256;

  float* out = (float*)d_out;

  // 1. W -> bf16 + zero BN-partial buffers
  convw_kernel<<<1178, 256, 0, stream>>>(W1, W2, Wup, W1t, W2t, Wupt, parts);
  // 2. upsample (MFMA, masked 8-tap, atomic partials)
  up_mfma_kernel<<<1024, 256, 0, stream>>>(x1, up_src, up_off, Wupt, up_raw, upP1, upP2, N);
  // 3. concat -> bf16 (folds BN-up)
  concat_kernel<<<2048, 256, 0, stream>>>(up_raw, x2, x3, upP1, upP2, gup, bup, xb, N);
  // 4. conv1 (bf16 out, atomic partials)
  conv_kernel<96, true><<<NB2, 256, 0, stream>>>(xb, W1t, nbr, y1b, c1P1, c1P2, N);
  // 5. apply BN1 in place on bf16 (folds bn1)
  apply_bn_bf16_inplace<<<2048, 256, 0, stream>>>(y1b, c1P1, c1P2, g1, b1, N);
  // 6. conv2 (fp32 out into d_out, atomic partials)
  conv_kernel<64, false><<<NB2, 256, 0, stream>>>(y1b, W2t, nbr, out, c2P1, c2P2, N);
  // 7. apply BN2 in place (folds bn2)
  apply_bn_inplace<<<2048, 256, 0, stream>>>(out, c2P1, c2P2, g2, b2, N);
}